// Round 3
// baseline (502.598 us; speedup 1.0000x reference)
//
#include <hip/hip_runtime.h>

// o[i,u,j] = sum_{v<=u} t[v,j] * x[i,v,j]
// x: (b, n, d) fp32, t: (2n-2, d) fp32 (first n rows used), o: (b, n, d) fp32
// Single-pass chunked scan with decoupled lookback (ticket-ordered, deadlock-free).

typedef float f4 __attribute__((ext_vector_type(4)));

#define D   512
#define DV  128          // f4 columns
#define C   128          // chunks along sequence (L = n/C = 64)
#define BT  512          // threads per block
#define RS  4            // row groups per block (BT/DV)
#define RPT 16           // rows per thread (L/RS)

// flags: 0 = empty, 1 = partial ready, 2 = inclusive ready
__global__ __launch_bounds__(BT, 4) void k_lookback(
    const float* __restrict__ x, const float* __restrict__ t,
    float* __restrict__ o, int b, int n,
    unsigned* __restrict__ flags, unsigned* __restrict__ ticket,
    float* __restrict__ Spart, float* __restrict__ Sincl) {

  __shared__ unsigned s_vid;
  __shared__ f4 red[RS][DV];    // per-rowgroup column sums
  __shared__ f4 csum[DV];       // whole-chunk column sums
  __shared__ f4 pfx[DV];        // exclusive prefix for this chunk

  if (threadIdx.x == 0) s_vid = atomicAdd(ticket, 1u);
  __syncthreads();
  const unsigned vid = s_vid;           // ticket order == start order
  const int c = (int)(vid / (unsigned)b);
  const int i = (int)(vid % (unsigned)b);

  const int jv = threadIdx.x & (DV - 1);
  const int h  = threadIdx.x >> 7;      // wave-uniform (2 waves per h)
  const int L  = n / C;
  const size_t row0 = (size_t)c * L + (size_t)h * RPT;
  const f4* xp = (const f4*)x + ((size_t)i * n + row0) * DV + jv;
  const f4* tp = (const f4*)t + row0 * DV + jv;

  // Phase 1: weighted values in registers, per-thread partial sum.
  f4 p[RPT];
  f4 s = {0.f, 0.f, 0.f, 0.f};
#pragma unroll
  for (int v = 0; v < RPT; ++v) {
    p[v] = xp[(size_t)v * DV] * tp[(size_t)v * DV];
    s += p[v];
  }
  red[h][jv] = s;
  __syncthreads();

  // Column chunk-sums; publish partial (not needed for c==0).
  if (threadIdx.x < DV) {
    f4 cs = red[0][jv] + red[1][jv] + red[2][jv] + red[3][jv];
    csum[jv] = cs;
    if (c > 0) ((f4*)Spart)[(size_t)vid * DV + jv] = cs;
  }
  __syncthreads();
  if (c > 0 && threadIdx.x == 0) {
    __threadfence();   // all block stores happened-before (syncthreads) -> publish
    __hip_atomic_store(&flags[vid], 1u, __ATOMIC_RELEASE, __HIP_MEMORY_SCOPE_AGENT);
  }

  // Phase 2: wave 0 does the serial lookback walk.
  if (threadIdx.x < 64) {
    const int l = threadIdx.x;
    f4 pf0 = {0.f, 0.f, 0.f, 0.f}, pf1 = {0.f, 0.f, 0.f, 0.f};
    int cp = c - 1;
    while (cp >= 0) {
      const unsigned pidx = (unsigned)cp * (unsigned)b + (unsigned)i;
      unsigned st;
      do {
        st = __hip_atomic_load(&flags[pidx], __ATOMIC_ACQUIRE,
                               __HIP_MEMORY_SCOPE_AGENT);
      } while (st == 0u);
      const f4* Sp = (st == 2u ? (const f4*)Sincl : (const f4*)Spart)
                     + (size_t)pidx * DV;
      pf0 += Sp[l];
      pf1 += Sp[l + 64];
      if (st == 2u) break;
      --cp;
    }
    pfx[l]      = pf0;
    pfx[l + 64] = pf1;
    if (c + 1 < C) {                    // last chunk has no consumer
      f4* Si = (f4*)Sincl + (size_t)vid * DV;
      Si[l]      = pf0 + csum[l];
      Si[l + 64] = pf1 + csum[l + 64];
      __threadfence();
      if (l == 0)
        __hip_atomic_store(&flags[vid], 2u, __ATOMIC_RELEASE,
                           __HIP_MEMORY_SCOPE_AGENT);
    }
  }
  __syncthreads();

  // Phase 3: per-thread local scan seeded with prefix + lower row-groups.
  f4 acc = pfx[jv];
#pragma unroll
  for (int hh = 0; hh < RS - 1; ++hh)
    if (hh < h) acc += red[hh][jv];     // h is wave-uniform -> no divergence

  f4* op = (f4*)o + ((size_t)i * n + row0) * DV + jv;
#pragma unroll
  for (int v = 0; v < RPT; ++v) {
    acc += p[v];
    __builtin_nontemporal_store(acc, &op[(size_t)v * DV]);
  }
}

// ---------------- fallback path (odd shapes): R2's two-kernel version ----------
__global__ __launch_bounds__(DV * RS) void k_chunksum(
    const float* __restrict__ x, const float* __restrict__ t,
    float* __restrict__ S, int b, int n, int L) {
  const int c  = blockIdx.x / b;
  const int i  = blockIdx.x % b;
  const int jv = threadIdx.x & (DV - 1);
  const int h  = threadIdx.x >> 7;
  const int rows = L / RS;
  const size_t row0 = (size_t)c * L + (size_t)h * rows;
  const f4* xp = (const f4*)x + ((size_t)i * n + row0) * DV + jv;
  const f4* tp = (const f4*)t + row0 * DV + jv;
  f4 acc = {0.f, 0.f, 0.f, 0.f};
  for (int v = 0; v < rows; ++v) acc += xp[(size_t)v * DV] * tp[(size_t)v * DV];
  __shared__ f4 red[RS][DV];
  red[h][jv] = acc;
  __syncthreads();
  if (h == 0) {
    f4 s = red[0][jv] + red[1][jv] + red[2][jv] + red[3][jv];
    ((f4*)S)[((size_t)c * b + i) * DV + jv] = s;
  }
}

__global__ __launch_bounds__(DV) void k_out(
    const float* __restrict__ x, const float* __restrict__ t,
    const float* __restrict__ S, float* __restrict__ o, int b, int n, int L) {
  const int c  = blockIdx.x / b;
  const int i  = blockIdx.x % b;
  const int jv = threadIdx.x;
  f4 acc = {0.f, 0.f, 0.f, 0.f};
  const f4* Sp = (const f4*)S + (size_t)i * DV + jv;
  const size_t cstride = (size_t)b * DV;
  for (int cp = 0; cp < c; ++cp) acc += Sp[(size_t)cp * cstride];
  const size_t row0  = (size_t)c * L;
  const size_t xbase = ((size_t)i * n + row0) * DV + jv;
  const f4* xp = (const f4*)x + xbase;
  const f4* tp = (const f4*)t + row0 * DV + jv;
  f4*       op = (f4*)o + xbase;
  for (int v = 0; v < L; ++v) {
    acc += xp[(size_t)v * DV] * tp[(size_t)v * DV];
    op[(size_t)v * DV] = acc;
  }
}

__global__ __launch_bounds__(256) void k_naive(
    const float* __restrict__ x, const float* __restrict__ t,
    float* __restrict__ o, int b, int n) {
  const int tid = blockIdx.x * 256 + threadIdx.x;
  if (tid >= b * DV) return;
  const int i  = tid / DV;
  const int jv = tid % DV;
  const f4* xp = (const f4*)x + (size_t)i * n * DV + jv;
  const f4* tp = (const f4*)t + jv;
  f4*       op = (f4*)o + (size_t)i * n * DV + jv;
  f4 acc = {0.f, 0.f, 0.f, 0.f};
  for (int v = 0; v < n; ++v) {
    acc += xp[(size_t)v * DV] * tp[(size_t)v * DV];
    op[(size_t)v * DV] = acc;
  }
}

extern "C" void kernel_launch(void* const* d_in, const int* in_sizes, int n_in,
                              void* d_out, int out_size, void* d_ws, size_t ws_size,
                              hipStream_t stream) {
  const float* x = (const float*)d_in[0];
  const float* t = (const float*)d_in[1];
  float*       o = (float*)d_out;

  const long long t_elems = in_sizes[1];
  const int n = (int)((t_elems / D + 2) / 2);
  const int b = (int)((long long)in_sizes[0] / ((long long)n * D));

  const int nb = C * b;                              // blocks / scan tiles
  const size_t ctrl_bytes = 65536;                   // flags + ticket, zeroed
  const size_t s_bytes    = (size_t)nb * D * sizeof(float);
  const size_t need       = ctrl_bytes + 2 * s_bytes;

  if (n % C == 0 && (n / C) == RS * RPT && ws_size >= need) {
    unsigned* flags  = (unsigned*)d_ws;              // nb entries
    unsigned* ticket = (unsigned*)d_ws + nb;         // 1 entry
    float* Spart = (float*)((char*)d_ws + ctrl_bytes);
    float* Sincl = Spart + (size_t)nb * D;
    hipMemsetAsync(d_ws, 0, ctrl_bytes, stream);
    hipLaunchKernelGGL(k_lookback, dim3(nb), dim3(BT), 0, stream,
                       x, t, o, b, n, flags, ticket, Spart, Sincl);
  } else if (n % C == 0 && (n / C) % RS == 0 &&
             ws_size >= (size_t)nb * D * sizeof(float)) {
    const int L = n / C;
    float* S = (float*)d_ws;
    hipLaunchKernelGGL(k_chunksum, dim3(nb), dim3(DV * RS), 0, stream,
                       x, t, S, b, n, L);
    hipLaunchKernelGGL(k_out, dim3(nb), dim3(DV), 0, stream,
                       x, t, S, o, b, n, L);
  } else {
    const int threads = b * DV;
    hipLaunchKernelGGL(k_naive, dim3((threads + 255) / 256), dim3(256), 0, stream,
                       x, t, o, b, n);
  }
}